// Round 1
// baseline (338.337 us; speedup 1.0000x reference)
//
#include <hip/hip_runtime.h>

#define NB 32
#define NS 2048
#define ND 512
#define NA 64
#define NE 64

typedef __bf16 bf16x8 __attribute__((ext_vector_type(8)));
typedef float f32x4 __attribute__((ext_vector_type(4)));

__device__ __forceinline__ unsigned short f2bf(float f) {
    union { float f; unsigned u; } v; v.f = f;
    unsigned r = (v.u + 0x7fffu + ((v.u >> 16) & 1u)) >> 16;
    return (unsigned short)r;
}

// ---------------------------------------------------------------------------
// Kernel 1a: hypernet big GEMMs  emb[32,64] @ W[64,32768] -> bf16, packed
// directly into MFMA B-fragment order for the main kernel.
// Down frags: [b][nblk(4)][kch(16)][lane(64)][8]   (B[k=d][n=a] = w_down[a][d])
// Up   frags: [b][nblk(32)][kch(2)][lane(64)][8]   (B[k=a][n=d] = w_up[d][a])
// grid: 256 blocks (mat 0/1 x 128 col-chunks of 256), 256 threads
// ---------------------------------------------------------------------------
__global__ __launch_bounds__(256) void hyper_pack(
    const float* __restrict__ emb,
    const float* __restrict__ dwW, const float* __restrict__ dwb,
    const float* __restrict__ uwW, const float* __restrict__ uwb,
    unsigned short* __restrict__ wdfrag, unsigned short* __restrict__ wufrag) {
    __shared__ float Wt[64][256];
    __shared__ float embs[NB * NE];
    const int tid = threadIdx.x;
    const int bx = blockIdx.x;
    const int mat = bx >> 7;
    const int chunk = bx & 127;
    const int base = chunk * 256;
    const float* W = mat ? uwW : dwW;
    const float* bias = mat ? uwb : dwb;

    for (int i = tid; i < NB * NE; i += 256) embs[i] = emb[i];
    for (int k = 0; k < 64; ++k) Wt[k][tid] = W[(size_t)k * 32768 + base + tid];
    __syncthreads();

    const int col = base + tid;
    const float bv = bias[col];
    float acc[NB];
#pragma unroll
    for (int b = 0; b < NB; ++b) acc[b] = bv;

    for (int k0 = 0; k0 < 64; k0 += 4) {
        float w0 = Wt[k0][tid], w1 = Wt[k0 + 1][tid];
        float w2 = Wt[k0 + 2][tid], w3 = Wt[k0 + 3][tid];
#pragma unroll
        for (int b = 0; b < NB; ++b) {
            float4 e = *(const float4*)&embs[b * 64 + k0];
            acc[b] = fmaf(e.x, w0, acc[b]);
            acc[b] = fmaf(e.y, w1, acc[b]);
            acc[b] = fmaf(e.z, w2, acc[b]);
            acc[b] = fmaf(e.w, w3, acc[b]);
        }
    }

    if (mat == 0) {
        int a = col >> 9, d = col & 511;
        size_t idx0 = ((size_t)((a >> 4) * 16 + (d >> 5)) * 64 +
                       (((d & 31) >> 3) * 16 + (a & 15))) * 8 + (d & 7);
#pragma unroll
        for (int b = 0; b < NB; ++b) wdfrag[idx0 + (size_t)b * 32768] = f2bf(acc[b]);
    } else {
        int d = col >> 6, a = col & 63;
        size_t idx0 = ((size_t)((d >> 4) * 2 + (a >> 5)) * 64 +
                       (((a & 31) >> 3) * 16 + (d & 15))) * 8 + (a & 7);
#pragma unroll
        for (int b = 0; b < NB; ++b) wufrag[idx0 + (size_t)b * 32768] = f2bf(acc[b]);
    }
}

// ---------------------------------------------------------------------------
// Kernel 1b: the six small per-sample vectors, laid out per b as
// [pre_w 512][pre_b 512][post_w 512][post_b 512][b_up 512][b_down 64] = 2624 f32
// ---------------------------------------------------------------------------
__global__ __launch_bounds__(256) void hyper_vec(
    const float* __restrict__ emb,
    const float* __restrict__ pwW, const float* __restrict__ pwb,
    const float* __restrict__ pbW, const float* __restrict__ pbb,
    const float* __restrict__ powW, const float* __restrict__ powb,
    const float* __restrict__ pobW, const float* __restrict__ pobb,
    const float* __restrict__ ubW, const float* __restrict__ ubb,
    const float* __restrict__ dbW, const float* __restrict__ dbb,
    float* __restrict__ vecs) {
    int gid = blockIdx.x * 256 + threadIdx.x;
    if (gid >= NB * 2624) return;
    int b = gid / 2624;
    int r = gid - b * 2624;
    const float* W; const float* bias; int off, width;
    if (r < 2560) {
        int v = r >> 9; off = r & 511; width = 512;
        switch (v) {
            case 0:  W = pwW;  bias = pwb;  break;
            case 1:  W = pbW;  bias = pbb;  break;
            case 2:  W = powW; bias = powb; break;
            case 3:  W = pobW; bias = pobb; break;
            default: W = ubW;  bias = ubb;  break;
        }
    } else {
        off = r - 2560; width = 64; W = dbW; bias = dbb;
    }
    float acc = bias[off];
    const float* e = emb + b * 64;
#pragma unroll 8
    for (int k = 0; k < 64; ++k) acc = fmaf(e[k], W[k * width + off], acc);
    vecs[gid] = acc;
}

// ---------------------------------------------------------------------------
// Kernel 2: fused  preLN -> down(MFMA) -> relu -> up(MFMA) -> postLN -> +x
// One block = one (b, 64-row S-tile). 4 waves; wave w owns rows [16w,16w+16).
// ---------------------------------------------------------------------------
__global__ __launch_bounds__(256, 2) void fused_adapter(
    const float* __restrict__ inp,
    const unsigned short* __restrict__ wdfrag,
    const unsigned short* __restrict__ wufrag,
    const float* __restrict__ vecs,
    float* __restrict__ out) {
    __shared__ unsigned short z_lds[64][520];   // bf16 bits, +8 pad: 2-way banks
    __shared__ unsigned short mid_lds[64][72];

    const int tid = threadIdx.x;
    const int lane = tid & 63;
    const int wave = tid >> 6;
    const int lanelo = lane & 15;
    const int quad = lane >> 4;
    const int bx = blockIdx.x;
    const int b = bx >> 5;
    const int s0 = (bx & 31) * 64;

    const float* vb = vecs + b * 2624;
    const float* pre_w  = vb;
    const float* pre_b  = vb + 512;
    const float* post_w = vb + 1024;
    const float* post_b = vb + 1536;
    const float* b_up   = vb + 2048;
    const float* b_down = vb + 2560;

    const float* xblk = inp + ((size_t)(b * NS + s0)) * ND;

    // ---- Phase A: load + pre-LN -> z (bf16) in LDS ----
    const int d0 = lane * 4;
    const float4 pw0 = *(const float4*)(pre_w + d0);
    const float4 pw1 = *(const float4*)(pre_w + 256 + d0);
    const float4 pb0 = *(const float4*)(pre_b + d0);
    const float4 pb1 = *(const float4*)(pre_b + 256 + d0);

    for (int r = wave; r < 64; r += 4) {
        const float* xp = xblk + (size_t)r * ND;
        float4 x0 = *(const float4*)(xp + d0);
        float4 x1 = *(const float4*)(xp + 256 + d0);
        float s = x0.x + x0.y + x0.z + x0.w + x1.x + x1.y + x1.z + x1.w;
        float q = x0.x * x0.x + x0.y * x0.y + x0.z * x0.z + x0.w * x0.w +
                  x1.x * x1.x + x1.y * x1.y + x1.z * x1.z + x1.w * x1.w;
#pragma unroll
        for (int m = 1; m <= 32; m <<= 1) {
            s += __shfl_xor(s, m);
            q += __shfl_xor(q, m);
        }
        float mean = s * (1.0f / 512.0f);
        float var = q * (1.0f / 512.0f) - mean * mean;
        float rstd = rsqrtf(var + 1e-5f);
        float z0 = (x0.x - mean) * rstd * pw0.x + pb0.x;
        float z1 = (x0.y - mean) * rstd * pw0.y + pb0.y;
        float z2 = (x0.z - mean) * rstd * pw0.z + pb0.z;
        float z3 = (x0.w - mean) * rstd * pw0.w + pb0.w;
        float z4 = (x1.x - mean) * rstd * pw1.x + pb1.x;
        float z5 = (x1.y - mean) * rstd * pw1.y + pb1.y;
        float z6 = (x1.z - mean) * rstd * pw1.z + pb1.z;
        float z7 = (x1.w - mean) * rstd * pw1.w + pb1.w;
        unsigned lo0 = (unsigned)f2bf(z0) | ((unsigned)f2bf(z1) << 16);
        unsigned hi0 = (unsigned)f2bf(z2) | ((unsigned)f2bf(z3) << 16);
        unsigned lo1 = (unsigned)f2bf(z4) | ((unsigned)f2bf(z5) << 16);
        unsigned hi1 = (unsigned)f2bf(z6) | ((unsigned)f2bf(z7) << 16);
        *(uint2*)&z_lds[r][d0] = make_uint2(lo0, hi0);
        *(uint2*)&z_lds[r][256 + d0] = make_uint2(lo1, hi1);
    }
    __syncthreads();

    // ---- Phase B: down GEMM [16,512]x[512,64] + bias + relu -> mid_lds ----
    const int m0 = wave * 16;
    const unsigned short* wd = wdfrag + (size_t)b * 32768;
    f32x4 accd[4];
#pragma unroll
    for (int nt = 0; nt < 4; ++nt) accd[nt] = (f32x4){0.f, 0.f, 0.f, 0.f};
    const int arow = m0 + lanelo;
#pragma unroll
    for (int kc = 0; kc < 16; ++kc) {
        uint4 au = *(const uint4*)&z_lds[arow][kc * 32 + quad * 8];
        bf16x8 af = __builtin_bit_cast(bf16x8, au);
#pragma unroll
        for (int nt = 0; nt < 4; ++nt) {
            uint4 bu = *(const uint4*)(wd + (size_t)((nt * 16 + kc) * 64 + lane) * 8);
            bf16x8 bf = __builtin_bit_cast(bf16x8, bu);
            accd[nt] = __builtin_amdgcn_mfma_f32_16x16x32_bf16(af, bf, accd[nt], 0, 0, 0);
        }
    }
#pragma unroll
    for (int nt = 0; nt < 4; ++nt) {
        float bd = b_down[nt * 16 + lanelo];
#pragma unroll
        for (int r = 0; r < 4; ++r) {
            float v = fmaxf(accd[nt][r] + bd, 0.0f);
            mid_lds[m0 + quad * 4 + r][nt * 16 + lanelo] = f2bf(v);
        }
    }
    __syncthreads();

    // ---- Phase C: up GEMM [16,64]x[64,512] + b_up + post-LN + residual ----
    uint4 a0u = *(const uint4*)&mid_lds[m0 + lanelo][quad * 8];
    uint4 a1u = *(const uint4*)&mid_lds[m0 + lanelo][32 + quad * 8];
    bf16x8 af0 = __builtin_bit_cast(bf16x8, a0u);
    bf16x8 af1 = __builtin_bit_cast(bf16x8, a1u);
    const unsigned short* wu = wufrag + (size_t)b * 32768;
    f32x4 acc[32];
#pragma unroll
    for (int nt = 0; nt < 32; ++nt) acc[nt] = (f32x4){0.f, 0.f, 0.f, 0.f};
#pragma unroll
    for (int nt = 0; nt < 32; ++nt) {
        uint4 b0u = *(const uint4*)(wu + (size_t)((nt * 2 + 0) * 64 + lane) * 8);
        uint4 b1u = *(const uint4*)(wu + (size_t)((nt * 2 + 1) * 64 + lane) * 8);
        acc[nt] = __builtin_amdgcn_mfma_f32_16x16x32_bf16(af0, __builtin_bit_cast(bf16x8, b0u), acc[nt], 0, 0, 0);
        acc[nt] = __builtin_amdgcn_mfma_f32_16x16x32_bf16(af1, __builtin_bit_cast(bf16x8, b1u), acc[nt], 0, 0, 0);
    }

    float sum[4] = {0.f, 0.f, 0.f, 0.f}, sq[4] = {0.f, 0.f, 0.f, 0.f};
#pragma unroll
    for (int nt = 0; nt < 32; ++nt) {
        float bu = b_up[nt * 16 + lanelo];
#pragma unroll
        for (int r = 0; r < 4; ++r) {
            float v = acc[nt][r] + bu;
            acc[nt][r] = v;
            sum[r] += v;
            sq[r] += v * v;
        }
    }
#pragma unroll
    for (int r = 0; r < 4; ++r) {
#pragma unroll
        for (int m = 1; m <= 8; m <<= 1) {
            sum[r] += __shfl_xor(sum[r], m);
            sq[r] += __shfl_xor(sq[r], m);
        }
    }
    float mean[4], rstd[4];
#pragma unroll
    for (int r = 0; r < 4; ++r) {
        mean[r] = sum[r] * (1.0f / 512.0f);
        float var = sq[r] * (1.0f / 512.0f) - mean[r] * mean[r];
        rstd[r] = rsqrtf(var + 1e-5f);
    }

    const float* xwave = xblk + (size_t)m0 * ND;
    float* owave = out + ((size_t)(b * NS + s0 + m0)) * ND;
#pragma unroll
    for (int nt = 0; nt < 32; ++nt) {
        int col = nt * 16 + lanelo;
        float w = post_w[col], bb = post_b[col];
#pragma unroll
        for (int r = 0; r < 4; ++r) {
            size_t off = (size_t)(quad * 4 + r) * ND + col;
            owave[off] = (acc[nt][r] - mean[r]) * rstd[r] * w + bb + xwave[off];
        }
    }
}

// ---------------------------------------------------------------------------
extern "C" void kernel_launch(void* const* d_in, const int* in_sizes, int n_in,
                              void* d_out, int out_size, void* d_ws, size_t ws_size,
                              hipStream_t stream) {
    const float* emb  = (const float*)d_in[0];
    const float* inp  = (const float*)d_in[1];
    const float* dwW  = (const float*)d_in[2];
    const float* dwb  = (const float*)d_in[3];
    const float* dbW  = (const float*)d_in[4];
    const float* dbb  = (const float*)d_in[5];
    const float* uwW  = (const float*)d_in[6];
    const float* uwb  = (const float*)d_in[7];
    const float* ubW  = (const float*)d_in[8];
    const float* ubb  = (const float*)d_in[9];
    const float* pwW  = (const float*)d_in[10];
    const float* pwb  = (const float*)d_in[11];
    const float* pbW  = (const float*)d_in[12];
    const float* pbb  = (const float*)d_in[13];
    const float* powW = (const float*)d_in[14];
    const float* powb = (const float*)d_in[15];
    const float* pobW = (const float*)d_in[16];
    const float* pobb = (const float*)d_in[17];

    unsigned short* wdfrag = (unsigned short*)d_ws;
    unsigned short* wufrag = wdfrag + (size_t)NB * 32768;
    float* vecs = (float*)(wufrag + (size_t)NB * 32768);

    hyper_pack<<<256, 256, 0, stream>>>(emb, dwW, dwb, uwW, uwb, wdfrag, wufrag);
    hyper_vec<<<(NB * 2624 + 255) / 256, 256, 0, stream>>>(
        emb, pwW, pwb, pbW, pbb, powW, powb, pobW, pobb, ubW, ubb, dbW, dbb, vecs);
    fused_adapter<<<NB * (NS / 64), 256, 0, stream>>>(
        inp, wdfrag, wufrag, vecs, (float*)d_out);
}